// Round 5
// baseline (16074.278 us; speedup 1.0000x reference)
//
#include <hip/hip_runtime.h>
#include <math.h>

#define BB 64      // batch
#define SS 512     // seq len
#define EE 128     // embed dim
#define HH 256     // hidden
#define NC 9       // classes
#define G4 1024    // 4*H gates (one direction)
#define TCLOG 7
#define TC 128     // time chunk
#define NCH (SS / TC)

#define ALD(p)    __hip_atomic_load((p), __ATOMIC_RELAXED, __HIP_MEMORY_SCOPE_AGENT)
#define AST(p,v)  __hip_atomic_store((p), (v), __ATOMIC_RELAXED, __HIP_MEMORY_SCOPE_AGENT)
#define AADD(p,v) __hip_atomic_fetch_add((p), (v), __ATOMIC_RELAXED, __HIP_MEMORY_SCOPE_AGENT)

// ---------- activations (overflow-safe, fast) ----------
__device__ __forceinline__ float sigf(float x) {
    return 1.0f / (1.0f + __expf(-x));
}
__device__ __forceinline__ float tanhfast(float x) {
    float a = fabsf(x);
    float e = __expf(-2.0f * a);
    float t = (1.0f - e) / (1.0f + e);
    return copysignf(t, x);
}

__global__ void zero_k(float* p, int n) {
    int i = blockIdx.x * 256 + threadIdx.x;
    if (i < n) p[i] = 0.f;
}

// ---------- tiled f32 GEMM (proven round-3): out[m][n] = A . W[n] + bias ----------
template <int KDIM, bool GATHER>
__global__ __launch_bounds__(256) void gemm_xg(
    const float* __restrict__ A, const int* __restrict__ tokens,
    const float* __restrict__ W, const float* __restrict__ bias,
    float* __restrict__ out, int t_base, int t_sign)
{
    __shared__ float As[16][68];
    __shared__ float Bs[16][68];
    const int tid = threadIdx.x;
    const int m0 = blockIdx.x * 64;
    const int n0 = blockIdx.y * 64;

    const int lr = tid >> 2;
    const int lk = (tid & 3) * 4;
    const int mload = m0 + lr;
    const int tcc = mload & (TC - 1);
    const int b   = mload >> TCLOG;
    const int tglob = t_base + t_sign * tcc;
    const long arow = (long)b * SS + tglob;
    const float* Ap = GATHER ? (A + (long)tokens[arow] * KDIM + lk)
                             : (A + arow * (long)KDIM + lk);
    const float* Wp = W + (long)(n0 + lr) * KDIM + lk;

    const int tr = tid >> 4;
    const int tn = tid & 15;

    float acc[4][4];
    #pragma unroll
    for (int i = 0; i < 4; i++)
        #pragma unroll
        for (int j = 0; j < 4; j++) acc[i][j] = 0.f;

    #pragma unroll 1
    for (int k0 = 0; k0 < KDIM; k0 += 16) {
        float4 av = *(const float4*)(Ap + k0);
        float4 bv = *(const float4*)(Wp + k0);
        As[lk + 0][lr] = av.x; As[lk + 1][lr] = av.y;
        As[lk + 2][lr] = av.z; As[lk + 3][lr] = av.w;
        Bs[lk + 0][lr] = bv.x; Bs[lk + 1][lr] = bv.y;
        Bs[lk + 2][lr] = bv.z; Bs[lk + 3][lr] = bv.w;
        __syncthreads();
        #pragma unroll
        for (int kk = 0; kk < 16; kk++) {
            float a[4], w[4];
            *(float4*)a = *(const float4*)&As[kk][tr * 4];
            *(float4*)w = *(const float4*)&Bs[kk][tn * 4];
            #pragma unroll
            for (int i = 0; i < 4; i++)
                #pragma unroll
                for (int j = 0; j < 4; j++) acc[i][j] = fmaf(a[i], w[j], acc[i][j]);
        }
        __syncthreads();
    }

    float4 bc = *(const float4*)(bias + n0 + tn * 4);
    #pragma unroll
    for (int i = 0; i < 4; i++) {
        float4 r;
        r.x = acc[i][0] + bc.x; r.y = acc[i][1] + bc.y;
        r.z = acc[i][2] + bc.z; r.w = acc[i][3] + bc.w;
        *(float4*)(out + (long)(m0 + tr * 4 + i) * G4 + n0 + tn * 4) = r;
    }
}

// ---------- persistent LSTM scan ----------
// grid (16 kslice, 8 rowgroup, 2 dir), 512 threads = 64 jr x 8 kq.
// Weights in VGPRs (32/thread). h exchanged via agent-scope global hx[par].
__global__ __launch_bounds__(512) void lstm_pscan(
    const float* __restrict__ xgF, const float* __restrict__ xgB, // [B][TC][1024]
    const float* __restrict__ whh,   // [2][1024][256]
    const float* __restrict__ bhh2,  // [2][1024]
    float* __restrict__ hout,        // [B*S][512]
    float* hx,                       // [2 par][2 d][256][64]
    float* cx,                       // [2 d][256][64]
    int* flags,                      // [16]
    int base, int tbF, int tbB)
{
    const int s = blockIdx.x;          // 0..15  k-slice
    const int g = blockIdx.y;          // 0..7   row group
    const int d = blockIdx.z;          // 0..1   direction
    const int t = threadIdx.x;
    const int jr = t >> 3;             // 0..63 local gate row
    const int kq = t & 7;              // 0..7  k-slice-of-32 within 256
    const int m  = jr >> 4;            // gate type 0..3
    const int kk = jr & 15;
    const int jg = m * 256 + s * 16 + kk;   // gate row within direction
    const int R0 = g * 8;
    const float* xg = d ? xgB : xgF;

    __shared__ __align__(16) float hl[256][8];
    __shared__ __align__(16) float gl[64][8];

    // ---- weights into registers (32 floats) ----
    float4 wv[8];
    const float* wp = whh + ((long)(d * 1024 + jg)) * 256 + kq * 32;
    #pragma unroll
    for (int i = 0; i < 8; i++) wv[i] = *(const float4*)(wp + i * 4);
    const float bj = bhh2[d * G4 + jg];

    // ---- cell-state owners: t<128 -> (r = t>>4, kc = t&15) ----
    const int rr = t >> 4, kc = t & 15;
    float c_reg = 0.f;
    if (t < 128) c_reg = cx[((long)(d * 256 + s * 16 + kc)) * 64 + R0 + rr];

    const int fi = d * 8 + g;

    for (int tc = 0; tc < TC; ++tc) {
        const int n = base + tc;
        const int par = n & 1;
        // 1) wait: all 16 siblings finished step n-1
        if (t == 0) {
            long it = 0;
            while (ALD(&flags[fi]) < 16 * n) {
                __builtin_amdgcn_s_sleep(2);
                if (++it > 200000000L) break;   // bail: wrong answer, never hang
            }
        }
        __syncthreads();
        // 2) fill hl from hx[par] (agent-scope loads)
        {
            const int v = t * 4;
            const int k = v >> 3, r4 = v & 7;
            const float* hp = hx + (((long)(par * 2 + d) * 256 + k)) * 64 + R0 + r4;
            float a0 = ALD(hp + 0), a1 = ALD(hp + 1), a2 = ALD(hp + 2), a3 = ALD(hp + 3);
            hl[k][r4 + 0] = a0; hl[k][r4 + 1] = a1;
            hl[k][r4 + 2] = a2; hl[k][r4 + 3] = a3;
        }
        __syncthreads();
        // 3) gate partials: acc[r] += w[k] * h[k][r], k in [kq*32, kq*32+32)
        float acc[8];
        #pragma unroll
        for (int q = 0; q < 8; q++) acc[q] = 0.f;
        #pragma unroll
        for (int i4 = 0; i4 < 8; i4++) {
            const float4 w4 = wv[i4];
            const int kb = kq * 32 + i4 * 4;
            #pragma unroll
            for (int c4 = 0; c4 < 4; c4++) {
                const float w = c4 == 0 ? w4.x : c4 == 1 ? w4.y : c4 == 2 ? w4.z : w4.w;
                const float4 ha = *(const float4*)&hl[kb + c4][0];
                const float4 hb = *(const float4*)&hl[kb + c4][4];
                acc[0] = fmaf(w, ha.x, acc[0]); acc[1] = fmaf(w, ha.y, acc[1]);
                acc[2] = fmaf(w, ha.z, acc[2]); acc[3] = fmaf(w, ha.w, acc[3]);
                acc[4] = fmaf(w, hb.x, acc[4]); acc[5] = fmaf(w, hb.y, acc[5]);
                acc[6] = fmaf(w, hb.z, acc[6]); acc[7] = fmaf(w, hb.w, acc[7]);
            }
        }
        // reduce over kq (lane bits 0..2)
        #pragma unroll
        for (int o = 1; o < 8; o <<= 1)
            #pragma unroll
            for (int q = 0; q < 8; q++) acc[q] += __shfl_xor(acc[q], o, 64);
        if (kq == 0) {
            #pragma unroll
            for (int r = 0; r < 8; r++) {
                float xv = xg[((long)((R0 + r) * TC + tc)) * G4 + jg];
                gl[jr][r] = acc[r] + bj + xv;
            }
        }
        __syncthreads();
        // 4) cell update + h publish
        if (t < 128) {
            float gi = gl[kc][rr], gf = gl[16 + kc][rr], gg = gl[32 + kc][rr], go = gl[48 + kc][rr];
            c_reg = sigf(gf) * c_reg + sigf(gi) * tanhfast(gg);
            float h = sigf(go) * tanhfast(c_reg);
            const int ko = s * 16 + kc;
            AST(hx + (((long)((par ^ 1) * 2 + d) * 256 + ko)) * 64 + R0 + rr, h);
            const int tg = d ? (tbB - tc) : (tbF + tc);
            hout[((long)((R0 + rr) * SS + tg)) * 512 + d * 256 + ko] = h;
        }
        __syncthreads();   // drains vmcnt for ALL threads -> stores visible before signal
        if (t == 0) AADD(&flags[fi], 1);
    }
    if (t < 128) cx[((long)(d * 256 + s * 16 + kc)) * 64 + R0 + rr] = c_reg;
}

// ---------- emissions ----------
__global__ __launch_bounds__(256) void emissions_k(
    const float* __restrict__ h1, const float* __restrict__ clsw,
    const float* __restrict__ clsb, float* __restrict__ em)
{
    long u = (long)blockIdx.x * 256 + threadIdx.x;
    if (u >= (long)BB * SS * NC) return;
    int c = (int)(u % NC);
    long m = u / NC;
    const float4* hr = (const float4*)(h1 + m * 512);
    const float4* wr = (const float4*)(clsw + (long)c * 512);
    float s0 = 0, s1 = 0, s2 = 0, s3 = 0;
    #pragma unroll 8
    for (int q = 0; q < 128; q += 4) {
        float4 a0 = hr[q],     w0 = wr[q];
        float4 a1 = hr[q + 1], w1 = wr[q + 1];
        float4 a2 = hr[q + 2], w2 = wr[q + 2];
        float4 a3 = hr[q + 3], w3 = wr[q + 3];
        s0 += a0.x * w0.x + a0.y * w0.y + a0.z * w0.z + a0.w * w0.w;
        s1 += a1.x * w1.x + a1.y * w1.y + a1.z * w1.z + a1.w * w1.w;
        s2 += a2.x * w2.x + a2.y * w2.y + a2.z * w2.z + a2.w * w2.w;
        s3 += a3.x * w3.x + a3.y * w3.y + a3.z * w3.z + a3.w * w3.w;
    }
    em[u] = (s0 + s1) + (s2 + s3) + clsb[c];
}

// ---------- CRF log-likelihood per batch row ----------
__global__ __launch_bounds__(64) void crf_llh(
    const float* __restrict__ em, const int* __restrict__ labels,
    const int* __restrict__ mask, const float* __restrict__ start,
    const float* __restrict__ endt, const float* __restrict__ trans,
    float* __restrict__ llh)
{
    int b = blockIdx.x, j = threadIdx.x;
    bool act = j < NC;
    float tcol[NC];
    #pragma unroll
    for (int i = 0; i < NC; i++) tcol[i] = act ? trans[i * NC + j] : 0.f;
    const float* emb_ = em + (long)b * SS * NC;
    const int* lb = labels + b * SS;
    const int* mk = mask + b * SS;
    float alpha = act ? (start[j] + emb_[j]) : -1e30f;

    float num = 0.f;
    int msum = 0;
    for (int t = j; t < SS; t += 64) msum += (mk[t] != 0);
    for (int t = 1 + j; t < SS; t += 64) {
        float m = (float)mk[t];
        num += m * (trans[lb[t - 1] * NC + lb[t]] + emb_[t * NC + lb[t]]);
    }
    for (int o = 32; o > 0; o >>= 1) {
        num  += __shfl_down(num, o);
        msum += __shfl_down(msum, o);
    }
    msum = __shfl(msum, 0);

    for (int t = 1; t < SS; t++) {
        int m = mk[t];
        float emj = act ? emb_[t * NC + j] : 0.f;
        float v[NC];
        float mx = -1e30f;
        #pragma unroll
        for (int i = 0; i < NC; i++) {
            v[i] = __shfl(alpha, i) + tcol[i];
            mx = fmaxf(mx, v[i]);
        }
        float sum = 0.f;
        #pragma unroll
        for (int i = 0; i < NC; i++) sum += __expf(v[i] - mx);
        float nxt = mx + __logf(sum) + emj;
        if (m > 0 && act) alpha = nxt;
    }
    float fin = act ? alpha + endt[j] : -1e30f;
    float mx = -1e30f;
    #pragma unroll
    for (int i = 0; i < NC; i++) mx = fmaxf(mx, __shfl(fin, i));
    float s = 0.f;
    #pragma unroll
    for (int i = 0; i < NC; i++) s += __expf(__shfl(fin, i) - mx);
    float den = mx + __logf(s);
    if (j == 0) {
        int last_idx = msum - 1;
        float numer = num + start[lb[0]] + emb_[lb[0]] + endt[lb[last_idx]];
        llh[b] = numer - den;
    }
}

__global__ __launch_bounds__(64) void loss_k(const float* __restrict__ llh, float* __restrict__ out) {
    int j = threadIdx.x;
    float v = llh[j];
    for (int o = 32; o > 0; o >>= 1) v += __shfl_down(v, o);
    if (j == 0) out[0] = -v / 64.0f;
}

// ---------- Viterbi per batch row ----------
__global__ __launch_bounds__(64) void viterbi_k(
    const float* __restrict__ em, const int* __restrict__ mask,
    const float* __restrict__ start, const float* __restrict__ endt,
    const float* __restrict__ trans, float* __restrict__ outp)
{
    int b = blockIdx.x, j = threadIdx.x;
    bool act = j < NC;
    __shared__ unsigned char bp[SS][NC];
    float tcol[NC];
    #pragma unroll
    for (int i = 0; i < NC; i++) tcol[i] = act ? trans[i * NC + j] : 0.f;
    const float* emb_ = em + (long)b * SS * NC;
    const int* mk = mask + b * SS;
    float score = act ? (start[j] + emb_[j]) : -1e30f;

    for (int t = 1; t < SS; t++) {
        float best = 0.f;
        int bi = 0;
        #pragma unroll
        for (int i = 0; i < NC; i++) {
            float vv = __shfl(score, i) + tcol[i];
            if (i == 0 || vv > best) { best = vv; bi = i; }   // first-max (jnp.argmax)
        }
        int m = mk[t];
        float nxt = best + (act ? emb_[t * NC + j] : 0.f);
        if (act) {
            if (m > 0) { score = nxt; bp[t][j] = (unsigned char)bi; }
            else       { bp[t][j] = (unsigned char)j; }
        }
    }
    float fin = act ? score + endt[j] : -1e30f;
    float bestf = 0.f;
    int last = 0;
    #pragma unroll
    for (int i = 0; i < NC; i++) {
        float vv = __shfl(fin, i);
        if (i == 0 || vv > bestf) { bestf = vv; last = i; }
    }
    __syncthreads();
    if (j == 0) {
        int cur = last;
        outp[1 + (long)b * SS + (SS - 1)] = (float)cur;
        for (int t = SS - 1; t >= 1; t--) {
            cur = bp[t][cur];
            outp[1 + (long)b * SS + (t - 1)] = (float)cur;
        }
    }
}

extern "C" void kernel_launch(void* const* d_in, const int* in_sizes, int n_in,
                              void* d_out, int out_size, void* d_ws, size_t ws_size,
                              hipStream_t stream) {
    const int*   tok    = (const int*)d_in[0];
    const int*   lab    = (const int*)d_in[1];
    const int*   msk    = (const int*)d_in[2];
    const float* emb    = (const float*)d_in[3];
    const float* w_ih0  = (const float*)d_in[4];   // (2,1024,128)
    const float* w_hh0  = (const float*)d_in[5];   // (2,1024,256)
    const float* b_ih0  = (const float*)d_in[6];   // (2,1024)
    const float* b_hh0  = (const float*)d_in[7];
    const float* w_ih1  = (const float*)d_in[8];   // (2,1024,512)
    const float* w_hh1  = (const float*)d_in[9];
    const float* b_ih1  = (const float*)d_in[10];
    const float* b_hh1  = (const float*)d_in[11];
    const float* clsw   = (const float*)d_in[12];  // (9,512)
    const float* clsb   = (const float*)d_in[13];
    const float* startt = (const float*)d_in[14];
    const float* endt   = (const float*)d_in[15];
    const float* transm = (const float*)d_in[16];
    float* out = (float*)d_out;

    // ---- workspace carve (f32 elements); ~202 MB, < proven round-3 fit ----
    size_t nH  = (size_t)BB * SS * 512;            // 16.78M each
    size_t nEM = (size_t)BB * SS * NC;
    size_t nXG = (size_t)BB * TC * G4;             // 8.39M each dir

    float* H0   = (float*)d_ws;
    float* H1   = H0 + nH;
    float* EM   = H1 + nH;
    float* LLH  = EM + nEM;
    float* XGF  = LLH + 64;
    float* XGB  = XGF + nXG;
    float* HX   = XGB + nXG;       // [2][2][256][64] = 65536
    float* CX   = HX + 65536;      // [2][256][64]    = 32768
    float* FLG  = CX + 32768;      // 64 ints
    int*   flags = (int*)FLG;

    size_t nZero = 65536 + 32768 + 64;   // hx + cx + flags contiguous

    dim3 gg((BB * TC) / 64, G4 / 64);    // (128, 16)
    dim3 sg(16, 8, 2);                   // kslice, rowgroup, dir

    // ---- layer 0 ----
    zero_k<<<(int)((nZero + 255) / 256), 256, 0, stream>>>(HX, (int)nZero);
    for (int c = 0; c < NCH; c++) {
        int tbF = c * TC;
        int tbB = SS - 1 - c * TC;
        gemm_xg<128, true><<<gg, 256, 0, stream>>>(emb, tok, w_ih0,              b_ih0,        XGF, tbF, +1);
        gemm_xg<128, true><<<gg, 256, 0, stream>>>(emb, tok, w_ih0 + 1024 * 128, b_ih0 + 1024, XGB, tbB, -1);
        lstm_pscan<<<sg, 512, 0, stream>>>(XGF, XGB, w_hh0, b_hh0, H0, HX, CX, flags, c * TC, tbF, tbB);
    }
    // ---- layer 1 ----
    zero_k<<<(int)((nZero + 255) / 256), 256, 0, stream>>>(HX, (int)nZero);
    for (int c = 0; c < NCH; c++) {
        int tbF = c * TC;
        int tbB = SS - 1 - c * TC;
        gemm_xg<512, false><<<gg, 256, 0, stream>>>(H0, nullptr, w_ih1,              b_ih1,        XGF, tbF, +1);
        gemm_xg<512, false><<<gg, 256, 0, stream>>>(H0, nullptr, w_ih1 + 1024 * 512, b_ih1 + 1024, XGB, tbB, -1);
        lstm_pscan<<<sg, 512, 0, stream>>>(XGF, XGB, w_hh1, b_hh1, H1, HX, CX, flags, c * TC, tbF, tbB);
    }

    emissions_k<<<((BB * SS * NC) + 255) / 256, 256, 0, stream>>>(H1, clsw, clsb, EM);
    crf_llh<<<BB, 64, 0, stream>>>(EM, lab, msk, startt, endt, transm, LLH);
    loss_k<<<1, 64, 0, stream>>>(LLH, out);
    viterbi_k<<<BB, 64, 0, stream>>>(EM, msk, startt, endt, transm, out);
}